// Round 6
// baseline (1714.344 us; speedup 1.0000x reference)
//
#include <hip/hip_runtime.h>
#include <hip/hip_fp16.h>

#define N_NODES 500000
#define N_EDGES 16000000
#define NB 1954          // ceil(N_NODES/256)
#define NPB_LOG 9
#define NPB 512          // nodes per bucket
#define NBUCK 977        // ceil(N_NODES/NPB)
#define NBUCK_PAD 1024
#define CH 32768         // edges per bucket_scatter block
#define NSB 489          // ceil(N_EDGES/CH)

// ---------- fp16 pack/unpack helpers (fp32 math everywhere else) ----------
__device__ __forceinline__ float2 up2(int p) {
    __half2 h = *reinterpret_cast<__half2*>(&p);
    return __half22float2(h);
}
__device__ __forceinline__ int pk2(float a, float b) {
    __half2 h = __floats2half2_rn(a, b);
    return *reinterpret_cast<int*>(&h);
}

// ============================================================================
// Two-level counting sort (LDS atomics) -> CSR (off, S)
// ============================================================================

__global__ void bucket_hist(const int* __restrict__ dst, int* __restrict__ ghist) {
    __shared__ int lhist[NBUCK_PAD];
    for (int t = threadIdx.x; t < NBUCK_PAD; t += 256) lhist[t] = 0;
    __syncthreads();
    int stride = gridDim.x * 256;
    for (int i = blockIdx.x * 256 + threadIdx.x; i < N_EDGES; i += stride) {
        atomicAdd(&lhist[dst[i] >> NPB_LOG], 1);
    }
    __syncthreads();
    for (int t = threadIdx.x; t < NBUCK_PAD; t += 256) {
        int c = lhist[t];
        if (c) atomicAdd(&ghist[t], c);
    }
}

__global__ void bucket_scan(int* __restrict__ gcur, int* __restrict__ bbase) {
    __shared__ int s[256];
    int t = threadIdx.x;
    int v[4], sum = 0, loc[4];
#pragma unroll
    for (int j = 0; j < 4; ++j) {
        v[j] = gcur[t * 4 + j];
        loc[j] = sum;
        sum += v[j];
    }
    s[t] = sum;
    __syncthreads();
    for (int o = 1; o < 256; o <<= 1) {
        int x = (t >= o) ? s[t - o] : 0;
        __syncthreads();
        s[t] += x;
        __syncthreads();
    }
    int excl = s[t] - sum;
#pragma unroll
    for (int j = 0; j < 4; ++j) {
        int e = excl + loc[j];
        bbase[t * 4 + j] = e;
        gcur[t * 4 + j] = e;
    }
    if (t == 255) bbase[NBUCK_PAD] = s[255];
}

__global__ void bucket_scatter(const int* __restrict__ src, const int* __restrict__ dst,
                               int* __restrict__ gcur, int* __restrict__ P) {
    __shared__ int lhist[NBUCK_PAD];
    __shared__ int lcur[NBUCK_PAD];
    for (int t = threadIdx.x; t < NBUCK_PAD; t += 256) lhist[t] = 0;
    __syncthreads();
    int e0 = blockIdx.x * CH;
    int e1 = min(e0 + CH, N_EDGES);
    for (int i = e0 + threadIdx.x; i < e1; i += 256) {
        atomicAdd(&lhist[dst[i] >> NPB_LOG], 1);
    }
    __syncthreads();
    for (int t = threadIdx.x; t < NBUCK_PAD; t += 256) {
        int c = lhist[t];
        lcur[t] = c ? atomicAdd(&gcur[t], c) : 0;
    }
    __syncthreads();
    for (int i = e0 + threadIdx.x; i < e1; i += 256) {
        int d = dst[i];
        int s = src[i];
        int b = d >> NPB_LOG;
        int pos = atomicAdd(&lcur[b], 1);
        P[pos] = ((d & (NPB - 1)) << 19) | s;
    }
}

__global__ void fine_sort(const int* __restrict__ P, const int* __restrict__ bbase,
                          int* __restrict__ off, int* __restrict__ S) {
    __shared__ int lhist[NPB];
    __shared__ int lexcl[NPB];
    __shared__ int sscan[256];
    int t = threadIdx.x;
    int b = blockIdx.x;
    int bb = bbase[b];
    int be = bbase[b + 1];
    int node0 = b << NPB_LOG;

    lhist[t] = 0;
    lhist[t + 256] = 0;
    __syncthreads();
    for (int j = bb + t; j < be; j += 256) {
        atomicAdd(&lhist[P[j] >> 19], 1);
    }
    __syncthreads();

    int a0 = lhist[2 * t], a1 = lhist[2 * t + 1];
    int ps = a0 + a1;
    sscan[t] = ps;
    __syncthreads();
    for (int o = 1; o < 256; o <<= 1) {
        int x = (t >= o) ? sscan[t - o] : 0;
        __syncthreads();
        sscan[t] += x;
        __syncthreads();
    }
    int pe = sscan[t] - ps;
    lexcl[2 * t] = pe;
    lexcl[2 * t + 1] = pe + a0;
    __syncthreads();

#pragma unroll
    for (int j = 0; j < 2; ++j) {
        int idx = t + j * 256;
        int ng = node0 + idx;
        if (ng < N_NODES) off[ng] = bb + lexcl[idx];
        lhist[idx] = lexcl[idx];
    }
    if (b == NBUCK - 1 && t == 0) off[N_NODES] = N_EDGES;
    __syncthreads();

    for (int j = bb + t; j < be; j += 256) {
        int p = P[j];
        int n = p >> 19;
        int s = p & 0x7FFFF;
        int pos = atomicAdd(&lhist[n], 1);
        S[bb + pos] = s;
    }
}

// ============================================================================
// fp16 table prep: x (fp32, 4 feats) -> xh (fp16, 8 B rows; 4 MB, L2-resident)
// ============================================================================

__global__ void convert_x(const float* __restrict__ x, int2* __restrict__ xh) {
    int i = blockIdx.x * 256 + threadIdx.x;
    if (i >= N_NODES) return;
    float4 v = ((const float4*)x)[i];
    int2 r;
    r.x = pk2(v.x, v.y);
    r.y = pk2(v.z, v.w);
    xh[i] = r;
}

// ============================================================================
// Fused layers. Split tables: A = bulk (HBM-path), B = tail (L2-resident).
//   h1: A int4 @16B stride (8 MB, feats 0-7) + B int @4B (2 MB, feats 8-9)
//   h2: A 2xint4 @32B stride (16 MB, feats 0-15) + B int2 @8B (4 MB, feats 16-19)
// ============================================================================

// Layer 1: gather xh (8 B rows, L2-resident), self from fp32 x
__global__ __launch_bounds__(256, 4) void fused_l1(
        const int* __restrict__ off, const int* __restrict__ ssrc,
        const int2* __restrict__ xh, const float* __restrict__ x,
        const float* __restrict__ wl, const float* __restrict__ bl,
        const float* __restrict__ wr,
        int4* __restrict__ h1A, int* __restrict__ h1B) {
    __shared__ float s_wl[40];
    __shared__ float s_wr[40];
    __shared__ float s_b[10];
    if (threadIdx.x < 40) {
        s_wl[threadIdx.x] = wl[threadIdx.x];
        s_wr[threadIdx.x] = wr[threadIdx.x];
    }
    if (threadIdx.x >= 64 && threadIdx.x < 74) s_b[threadIdx.x - 64] = bl[threadIdx.x - 64];
    __syncthreads();

    int i = blockIdx.x * 256 + threadIdx.x;
    if (i >= N_NODES) return;

    int b = off[i], e = off[i + 1];
    constexpr int UN = 8;

    float acc[4] = {0.f, 0.f, 0.f, 0.f};

    int k = b;
    for (; k + UN - 1 < e; k += UN) {
        int sidx[UN];
#pragma unroll
        for (int u = 0; u < UN; ++u) sidx[u] = ssrc[k + u];
        int2 v[UN];
#pragma unroll
        for (int u = 0; u < UN; ++u) v[u] = xh[sidx[u]];
#pragma unroll
        for (int u = 0; u < UN; ++u) {
            float2 f0 = up2(v[u].x), f1 = up2(v[u].y);
            acc[0] += f0.x; acc[1] += f0.y; acc[2] += f1.x; acc[3] += f1.y;
        }
    }
    for (; k < e; ++k) {
        int2 v = xh[ssrc[k]];
        float2 f0 = up2(v.x), f1 = up2(v.y);
        acc[0] += f0.x; acc[1] += f0.y; acc[2] += f1.x; acc[3] += f1.y;
    }

    float inv = 1.f / fmaxf((float)(e - b), 1.f);
#pragma unroll
    for (int q = 0; q < 4; ++q) acc[q] *= inv;

    float4 xs = ((const float4*)x)[i];
    float xv[4] = {xs.x, xs.y, xs.z, xs.w};

    float r[10];
#pragma unroll
    for (int j = 0; j < 10; ++j) {
        float t = s_b[j];
#pragma unroll
        for (int kk = 0; kk < 4; ++kk) {
            t += s_wl[j * 4 + kk] * acc[kk] + s_wr[j * 4 + kk] * xv[kk];
        }
        r[j] = fmaxf(t, 0.f);
    }
    int4 o0;
    o0.x = pk2(r[0], r[1]); o0.y = pk2(r[2], r[3]);
    o0.z = pk2(r[4], r[5]); o0.w = pk2(r[6], r[7]);
    h1A[i] = o0;
    h1B[i] = pk2(r[8], r[9]);
}

// Layer 2: gather h1A (16 B rows) + h1B (4 B rows, L2-resident)
__global__ __launch_bounds__(256, 4) void fused_l2(
        const int* __restrict__ off, const int* __restrict__ ssrc,
        const int4* __restrict__ h1A, const int* __restrict__ h1B,
        const float* __restrict__ wl, const float* __restrict__ bl,
        const float* __restrict__ wr,
        int4* __restrict__ h2A, int2* __restrict__ h2B) {
    __shared__ float s_wl[200];
    __shared__ float s_wr[200];
    __shared__ float s_b[20];
    if (threadIdx.x < 200) {
        s_wl[threadIdx.x] = wl[threadIdx.x];
        s_wr[threadIdx.x] = wr[threadIdx.x];
    }
    if (threadIdx.x >= 224 && threadIdx.x < 244) s_b[threadIdx.x - 224] = bl[threadIdx.x - 224];
    __syncthreads();

    int i = blockIdx.x * 256 + threadIdx.x;
    if (i >= N_NODES) return;

    int b = off[i], e = off[i + 1];
    constexpr int UN = 8;

    float acc[10];
#pragma unroll
    for (int q = 0; q < 10; ++q) acc[q] = 0.f;

    int k = b;
    for (; k + UN - 1 < e; k += UN) {
        int sidx[UN];
#pragma unroll
        for (int u = 0; u < UN; ++u) sidx[u] = ssrc[k + u];
        int4 va[UN];
        int vb[UN];
#pragma unroll
        for (int u = 0; u < UN; ++u) {
            va[u] = h1A[sidx[u]];
            vb[u] = h1B[sidx[u]];
        }
#pragma unroll
        for (int u = 0; u < UN; ++u) {
            float2 f0 = up2(va[u].x), f1 = up2(va[u].y), f2 = up2(va[u].z), f3 = up2(va[u].w), f4 = up2(vb[u]);
            acc[0] += f0.x; acc[1] += f0.y; acc[2] += f1.x; acc[3] += f1.y;
            acc[4] += f2.x; acc[5] += f2.y; acc[6] += f3.x; acc[7] += f3.y;
            acc[8] += f4.x; acc[9] += f4.y;
        }
    }
    for (; k < e; ++k) {
        int s = ssrc[k];
        int4 va = h1A[s];
        int vb = h1B[s];
        float2 f0 = up2(va.x), f1 = up2(va.y), f2 = up2(va.z), f3 = up2(va.w), f4 = up2(vb);
        acc[0] += f0.x; acc[1] += f0.y; acc[2] += f1.x; acc[3] += f1.y;
        acc[4] += f2.x; acc[5] += f2.y; acc[6] += f3.x; acc[7] += f3.y;
        acc[8] += f4.x; acc[9] += f4.y;
    }

    float inv = 1.f / fmaxf((float)(e - b), 1.f);
#pragma unroll
    for (int q = 0; q < 10; ++q) acc[q] *= inv;

    float xv[10];
    {
        int4 va = h1A[i];
        int vb = h1B[i];
        float2 f0 = up2(va.x), f1 = up2(va.y), f2 = up2(va.z), f3 = up2(va.w), f4 = up2(vb);
        xv[0] = f0.x; xv[1] = f0.y; xv[2] = f1.x; xv[3] = f1.y;
        xv[4] = f2.x; xv[5] = f2.y; xv[6] = f3.x; xv[7] = f3.y;
        xv[8] = f4.x; xv[9] = f4.y;
    }

    float r[20];
#pragma unroll
    for (int j = 0; j < 20; ++j) {
        float t = s_b[j];
#pragma unroll
        for (int kk = 0; kk < 10; ++kk) {
            t += s_wl[j * 10 + kk] * acc[kk] + s_wr[j * 10 + kk] * xv[kk];
        }
        r[j] = fmaxf(t, 0.f);
    }
    int4 o0, o1;
    o0.x = pk2(r[0], r[1]);   o0.y = pk2(r[2], r[3]);
    o0.z = pk2(r[4], r[5]);   o0.w = pk2(r[6], r[7]);
    o1.x = pk2(r[8], r[9]);   o1.y = pk2(r[10], r[11]);
    o1.z = pk2(r[12], r[13]); o1.w = pk2(r[14], r[15]);
    h2A[(long)i * 2] = o0;
    h2A[(long)i * 2 + 1] = o1;
    int2 o2;
    o2.x = pk2(r[16], r[17]); o2.y = pk2(r[18], r[19]);
    h2B[i] = o2;
}

// Layer 3 + classifier: gather h2A (32 B rows) + h2B (8 B rows, L2-resident)
__global__ __launch_bounds__(256, 4) void fused_l3(
        const int* __restrict__ off, const int* __restrict__ ssrc,
        const int4* __restrict__ h2A, const int2* __restrict__ h2B,
        const float* __restrict__ w3l, const float* __restrict__ b3,
        const float* __restrict__ w3r,
        const float* __restrict__ wc, const float* __restrict__ bc,
        float* __restrict__ out) {
    __shared__ float s_wl[400];
    __shared__ float s_wr[400];
    __shared__ float s_b[20];
    __shared__ float s_wc[160];
    __shared__ float s_bc[8];
    for (int t = threadIdx.x; t < 400; t += 256) {
        s_wl[t] = w3l[t];
        s_wr[t] = w3r[t];
    }
    if (threadIdx.x < 160) s_wc[threadIdx.x] = wc[threadIdx.x];
    if (threadIdx.x >= 192 && threadIdx.x < 212) s_b[threadIdx.x - 192] = b3[threadIdx.x - 192];
    if (threadIdx.x >= 224 && threadIdx.x < 232) s_bc[threadIdx.x - 224] = bc[threadIdx.x - 224];
    __syncthreads();

    int i = blockIdx.x * 256 + threadIdx.x;
    if (i >= N_NODES) return;

    int b = off[i], e = off[i + 1];
    constexpr int UN = 6;

    float acc[20];
#pragma unroll
    for (int q = 0; q < 20; ++q) acc[q] = 0.f;

    int k = b;
    for (; k + UN - 1 < e; k += UN) {
        int sidx[UN];
#pragma unroll
        for (int u = 0; u < UN; ++u) sidx[u] = ssrc[k + u];
        int4 va[UN], vb[UN];
        int2 vc[UN];
#pragma unroll
        for (int u = 0; u < UN; ++u) {
            va[u] = h2A[(long)sidx[u] * 2];
            vb[u] = h2A[(long)sidx[u] * 2 + 1];
            vc[u] = h2B[sidx[u]];
        }
#pragma unroll
        for (int u = 0; u < UN; ++u) {
            float2 f;
            f = up2(va[u].x); acc[0] += f.x; acc[1] += f.y;
            f = up2(va[u].y); acc[2] += f.x; acc[3] += f.y;
            f = up2(va[u].z); acc[4] += f.x; acc[5] += f.y;
            f = up2(va[u].w); acc[6] += f.x; acc[7] += f.y;
            f = up2(vb[u].x); acc[8] += f.x; acc[9] += f.y;
            f = up2(vb[u].y); acc[10] += f.x; acc[11] += f.y;
            f = up2(vb[u].z); acc[12] += f.x; acc[13] += f.y;
            f = up2(vb[u].w); acc[14] += f.x; acc[15] += f.y;
            f = up2(vc[u].x); acc[16] += f.x; acc[17] += f.y;
            f = up2(vc[u].y); acc[18] += f.x; acc[19] += f.y;
        }
    }
    for (; k < e; ++k) {
        int s = ssrc[k];
        int4 va = h2A[(long)s * 2];
        int4 vb = h2A[(long)s * 2 + 1];
        int2 vc = h2B[s];
        float2 f;
        f = up2(va.x); acc[0] += f.x; acc[1] += f.y;
        f = up2(va.y); acc[2] += f.x; acc[3] += f.y;
        f = up2(va.z); acc[4] += f.x; acc[5] += f.y;
        f = up2(va.w); acc[6] += f.x; acc[7] += f.y;
        f = up2(vb.x); acc[8] += f.x; acc[9] += f.y;
        f = up2(vb.y); acc[10] += f.x; acc[11] += f.y;
        f = up2(vb.z); acc[12] += f.x; acc[13] += f.y;
        f = up2(vb.w); acc[14] += f.x; acc[15] += f.y;
        f = up2(vc.x); acc[16] += f.x; acc[17] += f.y;
        f = up2(vc.y); acc[18] += f.x; acc[19] += f.y;
    }

    float inv = 1.f / fmaxf((float)(e - b), 1.f);
#pragma unroll
    for (int q = 0; q < 20; ++q) acc[q] *= inv;

    float xv[20];
    {
        int4 va = h2A[(long)i * 2];
        int4 vb = h2A[(long)i * 2 + 1];
        int2 vc = h2B[i];
        float2 f;
        f = up2(va.x); xv[0] = f.x; xv[1] = f.y;
        f = up2(va.y); xv[2] = f.x; xv[3] = f.y;
        f = up2(va.z); xv[4] = f.x; xv[5] = f.y;
        f = up2(va.w); xv[6] = f.x; xv[7] = f.y;
        f = up2(vb.x); xv[8] = f.x; xv[9] = f.y;
        f = up2(vb.y); xv[10] = f.x; xv[11] = f.y;
        f = up2(vb.z); xv[12] = f.x; xv[13] = f.y;
        f = up2(vb.w); xv[14] = f.x; xv[15] = f.y;
        f = up2(vc.x); xv[16] = f.x; xv[17] = f.y;
        f = up2(vc.y); xv[18] = f.x; xv[19] = f.y;
    }

    float h3[20];
#pragma unroll
    for (int j = 0; j < 20; ++j) {
        float r = s_b[j];
#pragma unroll
        for (int kk = 0; kk < 20; ++kk) {
            r += s_wl[j * 20 + kk] * acc[kk] + s_wr[j * 20 + kk] * xv[kk];
        }
        h3[j] = fmaxf(r, 0.f);
    }
#pragma unroll
    for (int j = 0; j < 8; ++j) {
        float r = s_bc[j];
#pragma unroll
        for (int kk = 0; kk < 20; ++kk) {
            r += s_wc[j * 20 + kk] * h3[kk];
        }
        out[(long)i * 8 + j] = r;
    }
}

// ============================================================================
// Path B (fallback, small ws): float-atomic version
// ============================================================================

__global__ void deg_kernel(const int* __restrict__ dst, int* __restrict__ deg) {
    int i = blockIdx.x * blockDim.x + threadIdx.x;
    if (i < N_EDGES) atomicAdd(&deg[dst[i]], 1);
}

template <int F>
__global__ void edge_agg(const int* __restrict__ src, const int* __restrict__ dst,
                         const float* __restrict__ h, float* __restrict__ agg) {
    int i = blockIdx.x * blockDim.x + threadIdx.x;
    if (i >= N_EDGES) return;
    int s = src[i];
    int d = dst[i];
    const float* hs = h + (long)s * F;
    float* ad = agg + (long)d * F;
#pragma unroll
    for (int f = 0; f < F; ++f) atomicAdd(&ad[f], hs[f]);
}

template <int FIN, int FOUT>
__global__ void node_apply(const float* __restrict__ agg, const float* __restrict__ hin,
                           const int* __restrict__ deg, const float* __restrict__ wl,
                           const float* __restrict__ bl, const float* __restrict__ wr,
                           float* __restrict__ hout) {
    __shared__ float s_wl[FOUT * FIN];
    __shared__ float s_wr[FOUT * FIN];
    __shared__ float s_b[FOUT];
    for (int t = threadIdx.x; t < FOUT * FIN; t += blockDim.x) {
        s_wl[t] = wl[t];
        s_wr[t] = wr[t];
    }
    for (int t = threadIdx.x; t < FOUT; t += blockDim.x) s_b[t] = bl[t];
    __syncthreads();
    int i = blockIdx.x * blockDim.x + threadIdx.x;
    if (i >= N_NODES) return;
    float inv = 1.0f / fmaxf((float)deg[i], 1.0f);
    float a[FIN], xv[FIN];
#pragma unroll
    for (int kk = 0; kk < FIN; ++kk) {
        a[kk] = agg[(long)i * FIN + kk] * inv;
        xv[kk] = hin[(long)i * FIN + kk];
    }
#pragma unroll
    for (int j = 0; j < FOUT; ++j) {
        float r = s_b[j];
#pragma unroll
        for (int kk = 0; kk < FIN; ++kk) r += s_wl[j * FIN + kk] * a[kk] + s_wr[j * FIN + kk] * xv[kk];
        hout[(long)i * FOUT + j] = fmaxf(r, 0.f);
    }
}

__global__ void node_final_old(const float* __restrict__ agg, const float* __restrict__ hin,
                               const int* __restrict__ deg, const float* __restrict__ w3l,
                               const float* __restrict__ b3, const float* __restrict__ w3r,
                               const float* __restrict__ wc, const float* __restrict__ bc,
                               float* __restrict__ out) {
    __shared__ float s_wl[400];
    __shared__ float s_wr[400];
    __shared__ float s_b[20];
    __shared__ float s_wc[160];
    __shared__ float s_bc[8];
    for (int t = threadIdx.x; t < 400; t += blockDim.x) {
        s_wl[t] = w3l[t];
        s_wr[t] = w3r[t];
    }
    for (int t = threadIdx.x; t < 160; t += blockDim.x) s_wc[t] = wc[t];
    for (int t = threadIdx.x; t < 20; t += blockDim.x) s_b[t] = b3[t];
    for (int t = threadIdx.x; t < 8; t += blockDim.x) s_bc[t] = bc[t];
    __syncthreads();
    int i = blockIdx.x * blockDim.x + threadIdx.x;
    if (i >= N_NODES) return;
    float inv = 1.0f / fmaxf((float)deg[i], 1.0f);
    float a[20], xv[20];
#pragma unroll
    for (int kk = 0; kk < 20; ++kk) {
        a[kk] = agg[(long)i * 20 + kk] * inv;
        xv[kk] = hin[(long)i * 20 + kk];
    }
    float h3[20];
#pragma unroll
    for (int j = 0; j < 20; ++j) {
        float r = s_b[j];
#pragma unroll
        for (int kk = 0; kk < 20; ++kk) r += s_wl[j * 20 + kk] * a[kk] + s_wr[j * 20 + kk] * xv[kk];
        h3[j] = fmaxf(r, 0.f);
    }
#pragma unroll
    for (int j = 0; j < 8; ++j) {
        float r = s_bc[j];
#pragma unroll
        for (int kk = 0; kk < 20; ++kk) r += s_wc[j * 20 + kk] * h3[kk];
        out[(long)i * 8 + j] = r;
    }
}

// ============================================================================

extern "C" void kernel_launch(void* const* d_in, const int* in_sizes, int n_in,
                              void* d_out, int out_size, void* d_ws, size_t ws_size,
                              hipStream_t stream) {
    const float* x = (const float*)d_in[0];
    const int* ei = (const int*)d_in[1];  // [2, E]: src row then dst row
    const float* w1l = (const float*)d_in[2];
    const float* b1 = (const float*)d_in[3];
    const float* w1r = (const float*)d_in[4];
    const float* w2l = (const float*)d_in[5];
    const float* b2 = (const float*)d_in[6];
    const float* w2r = (const float*)d_in[7];
    const float* w3l = (const float*)d_in[8];
    const float* b3 = (const float*)d_in[9];
    const float* w3r = (const float*)d_in[10];
    const float* wc = (const float*)d_in[11];
    const float* bc = (const float*)d_in[12];
    float* out = (float*)d_out;

    const int* src = ei;
    const int* dst = ei + N_EDGES;

    const int BT = 256;
    dim3 blk(BT);
    dim3 egrid((N_EDGES + BT - 1) / BT);
    dim3 ngrid(NB);

    // ---- Path A v5 layout (bytes):
    // off    [0,          2,000,128)
    // bbase  [2,000,128,  2,004,352)
    // gcur   [2,004,352,  2,008,448)
    // P      [2,008,448,  66,008,448)  16M packed ints (dead after fine_sort)
    //   xh   [2,008,448,   6,008,448)  overlay: 500K x 8 B
    //   h1A  [6,008,448,  14,008,448)  overlay: 500K x 16 B
    //   h1B  [14,008,448, 16,008,448)  overlay: 500K x 4 B
    //   h2A  [16,008,448, 32,008,448)  overlay: 500K x 32 B
    //   h2B  [32,008,448, 36,008,448)  overlay: 500K x 8 B
    // S      [66,008,448, 130,008,448) 16M sorted src
    const size_t NEED_A = 130008448;

    if (ws_size >= NEED_A) {
        char* ws = (char*)d_ws;
        int* off = (int*)ws;
        int* bbase = (int*)(ws + 2000128);
        int* gcur = (int*)(ws + 2004352);
        int* P = (int*)(ws + 2008448);
        int2* xh = (int2*)(ws + 2008448);
        int4* h1A = (int4*)(ws + 6008448);
        int* h1B = (int*)(ws + 14008448);
        int4* h2A = (int4*)(ws + 16008448);
        int2* h2B = (int2*)(ws + 32008448);
        int* S = (int*)(ws + 66008448);

        hipMemsetAsync(gcur, 0, NBUCK_PAD * sizeof(int), stream);
        bucket_hist<<<1024, blk, 0, stream>>>(dst, gcur);
        bucket_scan<<<1, blk, 0, stream>>>(gcur, bbase);
        bucket_scatter<<<NSB, blk, 0, stream>>>(src, dst, gcur, P);
        fine_sort<<<NBUCK, blk, 0, stream>>>(P, bbase, off, S);

        convert_x<<<ngrid, blk, 0, stream>>>(x, xh);
        fused_l1<<<ngrid, blk, 0, stream>>>(off, S, xh, x, w1l, b1, w1r, h1A, h1B);
        fused_l2<<<ngrid, blk, 0, stream>>>(off, S, h1A, h1B, w2l, b2, w2r, h2A, h2B);
        fused_l3<<<ngrid, blk, 0, stream>>>(off, S, h2A, h2B, w3l, b3, w3r, wc, bc, out);
    } else {
        // fallback: float-atomic path (needs 102 MB)
        char* ws = (char*)d_ws;
        int* deg = (int*)ws;
        float* agg = (float*)(ws + 2000000);
        float* h1 = (float*)(ws + 42000000);
        float* h2 = (float*)(ws + 62000000);

        hipMemsetAsync(deg, 0, (size_t)N_NODES * sizeof(int), stream);
        deg_kernel<<<egrid, blk, 0, stream>>>(dst, deg);

        hipMemsetAsync(agg, 0, (size_t)N_NODES * 4 * sizeof(float), stream);
        edge_agg<4><<<egrid, blk, 0, stream>>>(src, dst, x, agg);
        node_apply<4, 10><<<ngrid, blk, 0, stream>>>(agg, x, deg, w1l, b1, w1r, h1);

        hipMemsetAsync(agg, 0, (size_t)N_NODES * 10 * sizeof(float), stream);
        edge_agg<10><<<egrid, blk, 0, stream>>>(src, dst, h1, agg);
        node_apply<10, 20><<<ngrid, blk, 0, stream>>>(agg, h1, deg, w2l, b2, w2r, h2);

        hipMemsetAsync(agg, 0, (size_t)N_NODES * 20 * sizeof(float), stream);
        edge_agg<20><<<egrid, blk, 0, stream>>>(src, dst, h2, agg);
        node_final_old<<<ngrid, blk, 0, stream>>>(agg, h2, deg, w3l, b3, w3r, wc, bc, out);
    }
}